// Round 1
// baseline (109183.582 us; speedup 1.0000x reference)
//
#include <hip/hip_runtime.h>
#include <stdint.h>

// Problem dims
#define B_    64
#define T_    2048
#define IN_   64
#define H_    512
#define H2_   1024
#define OUT_  32
#define KTOT  (IN_ + H_)   // 576

// Grid config: 128 blocks = 16 batch-groups x 8 col-groups, 256 thr each.
// 128 blocks on 256 CUs -> co-residency guaranteed; spin barrier is safe.
#define NBLK  128
#define NTHR  256
#define CG    8            // column groups
#define BPG   4            // batches per batch-group

// ws layout (32-bit words)
// [0, 4096)  : one-shot barrier counters (never reused -> no reset races)
// [4096]     : abort flag (timeout failsafe)
// [8192, ..) : x ping-pong (2*B*H), xf (B*H), z (B*H)
#define CNT_WORDS 8192
#define ABORT_IDX 4096
#define XBUF_OFF  CNT_WORDS
#define XF_OFF    (XBUF_OFF + 2 * B_ * H_)
#define ZB_OFF    (XF_OFF + B_ * H_)

__global__ __launch_bounds__(256) void gru_init(float* ws, const float* __restrict__ x0) {
  int i = blockIdx.x * blockDim.x + threadIdx.x;
  int stride = gridDim.x * blockDim.x;
  unsigned* w = (unsigned*)ws;
  for (int k = i; k < CNT_WORDS; k += stride) w[k] = 0u;
  for (int k = i; k < B_ * H_; k += stride) ws[XBUF_OFF + k] = x0[k];
}

// Device-scope barrier over all NBLK blocks, one fresh counter per instance.
// Returns false if the failsafe tripped (co-residency failure) so all blocks
// bail out instead of hanging.
__device__ __forceinline__ bool gbar(unsigned* cnt, int idx) {
  __syncthreads();
  __shared__ int s_ok;
  if (threadIdx.x == 0) {
    unsigned* c = cnt + idx;
    __threadfence();  // publish prior global stores device-wide
    __hip_atomic_fetch_add(c, 1u, __ATOMIC_RELEASE, __HIP_MEMORY_SCOPE_AGENT);
    int ok = 1;
    int polls = 0;
    while (__hip_atomic_load(c, __ATOMIC_ACQUIRE, __HIP_MEMORY_SCOPE_AGENT) < (unsigned)NBLK) {
      __builtin_amdgcn_s_sleep(2);
      if ((++polls & 1023) == 0) {
        if (__hip_atomic_load(cnt + ABORT_IDX, __ATOMIC_RELAXED, __HIP_MEMORY_SCOPE_AGENT) != 0u ||
            polls > 2000000) {
          __hip_atomic_store(cnt + ABORT_IDX, 1u, __ATOMIC_RELAXED, __HIP_MEMORY_SCOPE_AGENT);
          ok = 0;
          break;
        }
      }
    }
    __threadfence();
    s_ok = ok;
  }
  __syncthreads();
  return s_ok != 0;
}

__global__ __launch_bounds__(NTHR) void gru_main(
    const float* __restrict__ u, const float* __restrict__ kfz,
    const float* __restrict__ bfz, const float* __restrict__ kr,
    const float* __restrict__ br, const float* __restrict__ wout,
    const float* __restrict__ bout, float* __restrict__ out, float* ws) {
  unsigned* cnt = (unsigned*)ws;
  float* xb0 = ws + XBUF_OFF;
  float* xb1 = xb0 + B_ * H_;
  float* xfb = ws + XF_OFF;
  float* zbb = ws + ZB_OFF;

  const int bg  = blockIdx.x >> 3;        // batch group: batches [4bg, 4bg+4)
  const int cg  = blockIdx.x & (CG - 1);  // column group
  const int tid = threadIdx.x;

  __shared__ float bufA[BPG][KTOT];  // u_t || x_t  (x_t = pre-update state)
  __shared__ float bufX[BPG][H_];    // f * x_t

  for (int t = 0; t < T_; ++t) {
    float* xcur = (t & 1) ? xb1 : xb0;
    float* xnxt = (t & 1) ? xb0 : xb1;

    // ---- stage u_t and x_t into LDS (coalesced) ----
    {
      int b = tid >> 6, i = tid & 63;
      bufA[b][i] = u[((size_t)(bg * BPG + b) * T_ + t) * IN_ + i];
    }
#pragma unroll
    for (int r = 0; r < (BPG * H_) / NTHR; ++r) {  // 8 iters
      int idx = r * NTHR + tid;
      int b = idx >> 9, k = idx & (H_ - 1);
      bufA[b][IN_ + k] = xcur[(bg * BPG + b) * H_ + k];
    }
    __syncthreads();

    // ---- phase A: fz = sigmoid(cat(u_t, x) @ Kfz + bfz) for our 128 cols ----
    {
      const int col = tid & 127;
      const int p   = tid >> 7;          // batch pair
      const int j   = cg * 128 + col;    // fz column in [0, 1024)
      const int b0  = 2 * p, b1 = 2 * p + 1;
      float a0 = bfz[j], a1 = bfz[j];
#pragma unroll 2
      for (int k = 0; k < KTOT; k += 4) {
        float w0 = kfz[(size_t)(k + 0) * H2_ + j];
        float w1 = kfz[(size_t)(k + 1) * H2_ + j];
        float w2 = kfz[(size_t)(k + 2) * H2_ + j];
        float w3 = kfz[(size_t)(k + 3) * H2_ + j];
        float4 xa = *(const float4*)&bufA[b0][k];
        float4 xc = *(const float4*)&bufA[b1][k];
        a0 += w0 * xa.x; a1 += w0 * xc.x;
        a0 += w1 * xa.y; a1 += w1 * xc.y;
        a0 += w2 * xa.z; a1 += w2 * xc.z;
        a0 += w3 * xa.w; a1 += w3 * xc.w;
      }
      float g0 = 1.0f / (1.0f + __expf(-a0));
      float g1 = 1.0f / (1.0f + __expf(-a1));
      int gb0 = bg * BPG + b0, gb1 = bg * BPG + b1;
      if (j < H_) {  // f half: publish f*x
        xfb[gb0 * H_ + j] = g0 * bufA[b0][IN_ + j];
        xfb[gb1 * H_ + j] = g1 * bufA[b1][IN_ + j];
      } else {       // z half
        zbb[gb0 * H_ + (j - H_)] = g0;
        zbb[gb1 * H_ + (j - H_)] = g1;
      }
    }

    if (!gbar(cnt, 2 * t)) return;

    // ---- stage xf into LDS ----
#pragma unroll
    for (int r = 0; r < (BPG * H_) / NTHR; ++r) {
      int idx = r * NTHR + tid;
      int b = idx >> 9, k = idx & (H_ - 1);
      bufX[b][k] = xfb[(bg * BPG + b) * H_ + k];
    }
    __syncthreads();

    // ---- phase B: r, state update (threads 0..127) | y output (threads 128..255) ----
    if (tid < 128) {
      const int col = tid & 63;
      const int p   = tid >> 6;
      const int j   = cg * 64 + col;     // r column in [0, 512)
      const int b0  = 2 * p, b1 = 2 * p + 1;
      float a0 = br[j], a1 = br[j];
#pragma unroll 2
      for (int k = 0; k < IN_; k += 4) {  // u part
        float w0 = kr[(size_t)(k + 0) * H_ + j];
        float w1 = kr[(size_t)(k + 1) * H_ + j];
        float w2 = kr[(size_t)(k + 2) * H_ + j];
        float w3 = kr[(size_t)(k + 3) * H_ + j];
        float4 xa = *(const float4*)&bufA[b0][k];
        float4 xc = *(const float4*)&bufA[b1][k];
        a0 += w0 * xa.x; a1 += w0 * xc.x;
        a0 += w1 * xa.y; a1 += w1 * xc.y;
        a0 += w2 * xa.z; a1 += w2 * xc.z;
        a0 += w3 * xa.w; a1 += w3 * xc.w;
      }
#pragma unroll 2
      for (int k = 0; k < H_; k += 4) {   // f*x part
        float w0 = kr[(size_t)(IN_ + k + 0) * H_ + j];
        float w1 = kr[(size_t)(IN_ + k + 1) * H_ + j];
        float w2 = kr[(size_t)(IN_ + k + 2) * H_ + j];
        float w3 = kr[(size_t)(IN_ + k + 3) * H_ + j];
        float4 xa = *(const float4*)&bufX[b0][k];
        float4 xc = *(const float4*)&bufX[b1][k];
        a0 += w0 * xa.x; a1 += w0 * xc.x;
        a0 += w1 * xa.y; a1 += w1 * xc.y;
        a0 += w2 * xa.z; a1 += w2 * xc.z;
        a0 += w3 * xa.w; a1 += w3 * xc.w;
      }
      // tanh(a) = 1 - 2/(1+exp(2a)); saturates correctly at +/-inf
      float e0 = __expf(2.0f * a0);
      float e1 = __expf(2.0f * a1);
      float r0 = 1.0f - 2.0f / (1.0f + e0);
      float r1 = 1.0f - 2.0f / (1.0f + e1);
      int gb0 = bg * BPG + b0, gb1 = bg * BPG + b1;
      float z0 = zbb[gb0 * H_ + j], z1 = zbb[gb1 * H_ + j];
      float xo0 = bufA[b0][IN_ + j], xo1 = bufA[b1][IN_ + j];
      xnxt[gb0 * H_ + j] = (1.0f - z0) * xo0 + z0 * r0;
      xnxt[gb1 * H_ + j] = (1.0f - z1) * xo1 + z1 * r1;
    } else {
      // y_t = x_t @ W_out^T + b_out (pre-update x, already in bufA).
      // 16 dots (4 batches x 4 out-cols for this cg), 8 threads per dot.
      int q    = tid - 128;
      int d    = q >> 3;               // 0..15
      int part = q & 7;                // 0..7, 64 elements each
      int b    = d >> 2;               // 0..3
      int oc   = (d & 3) + 4 * cg;     // 0..31 across cgs
      float acc = 0.0f;
      int kbase = part * 64;
#pragma unroll 4
      for (int k = 0; k < 64; k += 4) {
        float4 xa = *(const float4*)&bufA[b][IN_ + kbase + k];
        float4 wv = *(const float4*)&wout[(size_t)oc * H_ + kbase + k];
        acc += wv.x * xa.x + wv.y * xa.y + wv.z * xa.z + wv.w * xa.w;
      }
      acc += __shfl_down(acc, 4);
      acc += __shfl_down(acc, 2);
      acc += __shfl_down(acc, 1);
      if (part == 0)
        out[((size_t)(bg * BPG + b) * T_ + t) * OUT_ + oc] = acc + bout[oc];
    }

    if (!gbar(cnt, 2 * t + 1)) return;
  }
}

extern "C" void kernel_launch(void* const* d_in, const int* in_sizes, int n_in,
                              void* d_out, int out_size, void* d_ws, size_t ws_size,
                              hipStream_t stream) {
  const float* u    = (const float*)d_in[0];
  const float* x0   = (const float*)d_in[1];
  const float* kfz  = (const float*)d_in[2];
  const float* bfz  = (const float*)d_in[3];
  const float* kr   = (const float*)d_in[4];
  const float* br   = (const float*)d_in[5];
  const float* wout = (const float*)d_in[6];
  const float* bout = (const float*)d_in[7];
  float* out = (float*)d_out;
  float* ws  = (float*)d_ws;

  hipLaunchKernelGGL(gru_init, dim3(64), dim3(256), 0, stream, ws, x0);
  hipLaunchKernelGGL(gru_main, dim3(NBLK), dim3(NTHR), 0, stream,
                     u, kfz, bfz, kr, br, wout, bout, out, ws);
}

// Round 3
// 66764.233 us; speedup vs baseline: 1.6354x; 1.6354x over previous
//
#include <hip/hip_runtime.h>
#include <stdint.h>

// Problem dims
#define B_    64
#define T_    2048
#define IN_   64
#define H_    512
#define H2_   1024
#define OUT_  32
#define KTOT  576          // IN_ + H_

// Grid: 256 blocks = 8 batch-groups (bg = blockIdx & 7 -> XCD-local heuristic)
//                  x 32 col-groups. 256 threads/block.
#define NBG   8
#define NCG   32
#define NTHR  256
#define BPG   8            // batches per group
#define KSL   18           // k per slice (32 slices x 18 = 576)
#define RS    12           // bufA row stride in floats (16B-aligned rows, 2-way-max banks)

// ws layout (32-bit words)
// counters: idx = (2*t+ph)*8 + bg  -> max 4095*8+7 = 32767 < 32768
#define CNT_WORDS 32768
#define ABORT_IDX 32768
#define BUF_BASE  32832    // float4-aligned
#define XSLAB     32768    // words per slab: [8 bg][512 j][8 b]

__global__ __launch_bounds__(256) void gru_init(float* ws, const float* __restrict__ x0) {
  int i = blockIdx.x * blockDim.x + threadIdx.x;
  int stride = gridDim.x * blockDim.x;
  unsigned* w = (unsigned*)ws;
  for (int k = i; k <= ABORT_IDX; k += stride) w[k] = 0u;
  // xg0[bg][j][b] = x0[(bg*8+b)*512 + j]
  for (int k = i; k < NBG * H_ * BPG; k += stride) {
    int bg = k >> 12, j = (k >> 3) & (H_ - 1), b = k & 7;
    ws[BUF_BASE + k] = x0[(bg * 8 + b) * H_ + j];
  }
}

// Barrier among the 32 blocks of one batch group; one fresh counter per use.
__device__ __forceinline__ bool gbar(unsigned* cnt, int idx) {
  __syncthreads();
  __shared__ int s_ok;
  if (threadIdx.x == 0) {
    unsigned* c = cnt + idx;
    __threadfence();  // publish prior global stores device-wide
    __hip_atomic_fetch_add(c, 1u, __ATOMIC_RELEASE, __HIP_MEMORY_SCOPE_AGENT);
    int ok = 1;
    int polls = 0;
    while (__hip_atomic_load(c, __ATOMIC_ACQUIRE, __HIP_MEMORY_SCOPE_AGENT) < (unsigned)NCG) {
      __builtin_amdgcn_s_sleep(1);
      if ((++polls & 255) == 0) {
        if (__hip_atomic_load(cnt + ABORT_IDX, __ATOMIC_RELAXED, __HIP_MEMORY_SCOPE_AGENT) != 0u ||
            polls > 4000000) {
          __hip_atomic_store(cnt + ABORT_IDX, 1u, __ATOMIC_RELAXED, __HIP_MEMORY_SCOPE_AGENT);
          ok = 0;
          break;
        }
      }
    }
    __threadfence();
    s_ok = ok;
  }
  __syncthreads();
  return s_ok != 0;
}

__global__ __launch_bounds__(NTHR, 1) void gru_main(
    const float* __restrict__ u, const float* __restrict__ kfz,
    const float* __restrict__ bfz, const float* __restrict__ kr,
    const float* __restrict__ br, const float* __restrict__ wout,
    const float* __restrict__ bout, float* __restrict__ out, float* ws) {
  unsigned* cnt = (unsigned*)ws;
  float* xg0 = ws + BUF_BASE;
  float* xg1 = xg0 + XSLAB;
  float* xfg = xg1 + XSLAB;

  const int bg  = blockIdx.x & 7;    // same bg -> same XCD (heuristic, perf only)
  const int cg  = blockIdx.x >> 3;   // column group 0..31
  const int tid = threadIdx.x;
  const int w   = tid >> 6;          // wave 0..3
  const int l   = tid & 63;
  const int cq  = l & 7;             // col-quad 0..7
  const int g   = l >> 3;            // in-wave k-slice 0..7
  const int kb  = (w * 8 + g) * KSL; // this thread's k base (18 k's)
  const int fc  = tid >> 3;          // finalize col 0..31
  const int fb  = tid & 7;           // finalize batch 0..7
  const int yb  = tid >> 5;          // y batch 0..7
  const int yq  = tid & 31;          // y k-slice 0..31

  __shared__ float bufA[KTOT * RS];        // [k][12]: u_t(k<64) | x or f*x
  __shared__ float pA[4 * 32 * RS];        // cross-wave partials, phase A
  __shared__ float pB[4 * 16 * RS];        // cross-wave partials, phase B
  __shared__ float rbuf[16 * 8];           // r values for update threads

  // ---- one-time: weights into registers ----
  float wA[KSL][4];
#pragma unroll
  for (int i = 0; i < KSL; ++i)
#pragma unroll
    for (int m = 0; m < 4; ++m) {
      int c = 4 * cq + m;
      int gcol = (c < 16) ? (16 * cg + c) : (512 + 16 * cg + (c - 16));
      wA[i][m] = kfz[(size_t)(kb + i) * H2_ + gcol];
    }
  float wB[KSL][2];
#pragma unroll
  for (int i = 0; i < KSL; ++i)
#pragma unroll
    for (int m = 0; m < 2; ++m)
      wB[i][m] = kr[(size_t)(kb + i) * H_ + (16 * cg + 2 * cq + m)];
  float wy[16];
#pragma unroll
  for (int i = 0; i < 16; ++i) wy[i] = wout[cg * H_ + (yq + 32 * i)];
  const float by = bout[cg];
  const int fzc = (fc < 16) ? (16 * cg + fc) : (512 + 16 * cg + (fc - 16));
  const float biasA = bfz[fzc];
  const float biasB = (tid < 128) ? br[16 * cg + fc] : 0.0f;

  float zreg = 0.0f, xoldz = 0.0f;

  for (int t = 0; t < T_; ++t) {
    float* xcur = (t & 1) ? xg1 : xg0;
    float* xnxt = (t & 1) ? xg0 : xg1;

    // ---- stage u_t (64k x 8b) and x (512 x 8b) into bufA[k][12] ----
    {
      int k2 = tid & 31, b = tid >> 5;
      float2 uv = *(const float2*)&u[((size_t)(bg * 8 + b) * T_ + t) * IN_ + 2 * k2];
      bufA[(2 * k2) * RS + b] = uv.x;
      bufA[(2 * k2 + 1) * RS + b] = uv.y;
      const float* src = &xcur[(size_t)(bg * H_ + tid) * 8];
      float4 p0 = *(const float4*)src;
      float4 p1 = *(const float4*)(src + 4);
      *(float4*)&bufA[(64 + tid) * RS] = p0;
      *(float4*)&bufA[(64 + tid) * RS + 4] = p1;
      src = &xcur[(size_t)(bg * H_ + tid + 256) * 8];
      p0 = *(const float4*)src;
      p1 = *(const float4*)(src + 4);
      *(float4*)&bufA[(64 + tid + 256) * RS] = p0;
      *(float4*)&bufA[(64 + tid + 256) * RS + 4] = p1;
    }
    __syncthreads();

    // ---- phase A core: fz partials for 4 cols x 8 batches over 18 k ----
    float acc[4][8] = {};
#pragma unroll
    for (int i = 0; i < KSL; ++i) {
      const float* xr = &bufA[(kb + i) * RS];
      float4 x0 = *(const float4*)xr;
      float4 x1 = *(const float4*)(xr + 4);
#pragma unroll
      for (int m = 0; m < 4; ++m) {
        float wv = wA[i][m];
        acc[m][0] += wv * x0.x; acc[m][1] += wv * x0.y;
        acc[m][2] += wv * x0.z; acc[m][3] += wv * x0.w;
        acc[m][4] += wv * x1.x; acc[m][5] += wv * x1.y;
        acc[m][6] += wv * x1.z; acc[m][7] += wv * x1.w;
      }
    }

    // ---- y_t = x_t @ wout[cg] (uses pre-update x still in bufA) ----
    {
      float yp = 0.0f;
#pragma unroll
      for (int i = 0; i < 16; ++i)
        yp += wy[i] * bufA[(64 + yq + 32 * i) * RS + yb];
      yp += __shfl_xor(yp, 1);  yp += __shfl_xor(yp, 2);
      yp += __shfl_xor(yp, 4);  yp += __shfl_xor(yp, 8);
      yp += __shfl_xor(yp, 16);
      if (yq == 0)
        out[((size_t)(bg * 8 + yb) * T_ + t) * OUT_ + cg] = yp + by;
    }

    // ---- reduce A: xor over in-wave k-slices, then LDS across waves ----
#pragma unroll
    for (int m = 0; m < 4; ++m)
#pragma unroll
      for (int b = 0; b < 8; ++b) {
        acc[m][b] += __shfl_xor(acc[m][b], 8);
        acc[m][b] += __shfl_xor(acc[m][b], 16);
        acc[m][b] += __shfl_xor(acc[m][b], 32);
      }
    if (g == 0) {
#pragma unroll
      for (int m = 0; m < 4; ++m) {
        float* p = &pA[(w * 32 + 4 * cq + m) * RS];
        *(float4*)p = make_float4(acc[m][0], acc[m][1], acc[m][2], acc[m][3]);
        *(float4*)(p + 4) = make_float4(acc[m][4], acc[m][5], acc[m][6], acc[m][7]);
      }
    }
    __syncthreads();

    // ---- finalize A: sigmoid; publish f*x; stash z locally ----
    {
      float s = pA[(0 * 32 + fc) * RS + fb] + pA[(1 * 32 + fc) * RS + fb] +
                pA[(2 * 32 + fc) * RS + fb] + pA[(3 * 32 + fc) * RS + fb] + biasA;
      float sig = 1.0f / (1.0f + __expf(-s));
      if (fc < 16) {
        float xo = bufA[(64 + 16 * cg + fc) * RS + fb];
        xfg[(size_t)(bg * H_ + 16 * cg + fc) * 8 + fb] = sig * xo;
      } else {
        zreg = sig;
        xoldz = bufA[(64 + 16 * cg + (fc - 16)) * RS + fb];
      }
    }

    if (!gbar(cnt, (2 * t) * 8 + bg)) return;

    // ---- stage f*x into bufA (overwrites x part) ----
    {
      const float* src = &xfg[(size_t)(bg * H_ + tid) * 8];
      float4 p0 = *(const float4*)src;
      float4 p1 = *(const float4*)(src + 4);
      *(float4*)&bufA[(64 + tid) * RS] = p0;
      *(float4*)&bufA[(64 + tid) * RS + 4] = p1;
      src = &xfg[(size_t)(bg * H_ + tid + 256) * 8];
      p0 = *(const float4*)src;
      p1 = *(const float4*)(src + 4);
      *(float4*)&bufA[(64 + tid + 256) * RS] = p0;
      *(float4*)&bufA[(64 + tid + 256) * RS + 4] = p1;
    }
    __syncthreads();

    // ---- phase B core: r partials for 2 cols x 8 batches ----
    float acc2[2][8] = {};
#pragma unroll
    for (int i = 0; i < KSL; ++i) {
      const float* xr = &bufA[(kb + i) * RS];
      float4 x0 = *(const float4*)xr;
      float4 x1 = *(const float4*)(xr + 4);
#pragma unroll
      for (int m = 0; m < 2; ++m) {
        float wv = wB[i][m];
        acc2[m][0] += wv * x0.x; acc2[m][1] += wv * x0.y;
        acc2[m][2] += wv * x0.z; acc2[m][3] += wv * x0.w;
        acc2[m][4] += wv * x1.x; acc2[m][5] += wv * x1.y;
        acc2[m][6] += wv * x1.z; acc2[m][7] += wv * x1.w;
      }
    }
#pragma unroll
    for (int m = 0; m < 2; ++m)
#pragma unroll
      for (int b = 0; b < 8; ++b) {
        acc2[m][b] += __shfl_xor(acc2[m][b], 8);
        acc2[m][b] += __shfl_xor(acc2[m][b], 16);
        acc2[m][b] += __shfl_xor(acc2[m][b], 32);
      }
    if (g == 0) {
#pragma unroll
      for (int m = 0; m < 2; ++m) {
        float* p = &pB[(w * 16 + 2 * cq + m) * RS];
        *(float4*)p = make_float4(acc2[m][0], acc2[m][1], acc2[m][2], acc2[m][3]);
        *(float4*)(p + 4) = make_float4(acc2[m][4], acc2[m][5], acc2[m][6], acc2[m][7]);
      }
    }
    __syncthreads();

    // ---- finalize B: tanh -> rbuf ----
    if (tid < 128) {
      float s = pB[(0 * 16 + fc) * RS + fb] + pB[(1 * 16 + fc) * RS + fb] +
                pB[(2 * 16 + fc) * RS + fb] + pB[(3 * 16 + fc) * RS + fb] + biasB;
      float e = __expf(2.0f * s);
      rbuf[fc * 8 + fb] = 1.0f - 2.0f / (1.0f + e);
    }
    __syncthreads();

    // ---- update: x_next = x + z*(r - x), publish ----
    if (tid >= 128) {
      float r = rbuf[(fc - 16) * 8 + fb];
      float xn = xoldz + zreg * (r - xoldz);
      xnxt[(size_t)(bg * H_ + 16 * cg + (fc - 16)) * 8 + fb] = xn;
    }

    if (!gbar(cnt, (2 * t + 1) * 8 + bg)) return;
  }
}

extern "C" void kernel_launch(void* const* d_in, const int* in_sizes, int n_in,
                              void* d_out, int out_size, void* d_ws, size_t ws_size,
                              hipStream_t stream) {
  const float* u    = (const float*)d_in[0];
  const float* x0   = (const float*)d_in[1];
  const float* kfz  = (const float*)d_in[2];
  const float* bfz  = (const float*)d_in[3];
  const float* kr   = (const float*)d_in[4];
  const float* br   = (const float*)d_in[5];
  const float* wout = (const float*)d_in[6];
  const float* bout = (const float*)d_in[7];
  float* out = (float*)d_out;
  float* ws  = (float*)d_ws;

  hipLaunchKernelGGL(gru_init, dim3(64), dim3(256), 0, stream, ws, x0);
  hipLaunchKernelGGL(gru_main, dim3(NBG * NCG), dim3(NTHR), 0, stream,
                     u, kfz, bfz, kr, br, wout, bout, out, ws);
}

// Round 5
// 32460.867 us; speedup vs baseline: 3.3635x; 2.0568x over previous
//
#include <hip/hip_runtime.h>
#include <stdint.h>

// Problem dims
#define B_    64
#define T_    2048
#define IN_   64
#define H_    512
#define H2_   1024
#define OUT_  32
#define KTOT  576          // IN_ + H_

// Grid: 256 blocks = 8 batch-groups x 32 col-groups, 256 threads.
#define NBG   8
#define NCG   32
#define NTHR  256
#define BPG   8            // batches per group
#define KSL   18           // k per slice (32 slices x 18 = 576)
#define RS    12           // bufA row stride in floats

// ws layout (32-bit words)
// counters: idx = (bg*2 + ph)*2048 + t  -> each (bg,ph) gets its own 8KB
// region, so only its 32 blocks ever touch a given line (R3 had all 256
// blocks on ONE line -> MALL serialization was the 16us/barrier wall).
#define CNT_WORDS 32768
#define ABORT_IDX 32768
#define BUF_BASE  32832    // float4-aligned
#define XSLAB     32768    // words per slab: [8 bg][512 j][8 b]

// Agent-scope relaxed ops: scope bits route them to MALL (bypass L1/L2),
// so cross-XCD producer->consumer needs NO wbl2/inv fences at all.
__device__ __forceinline__ float gload(const float* p) {
  return __hip_atomic_load(p, __ATOMIC_RELAXED, __HIP_MEMORY_SCOPE_AGENT);
}
__device__ __forceinline__ void gstore(float* p, float v) {
  __hip_atomic_store(p, v, __ATOMIC_RELAXED, __HIP_MEMORY_SCOPE_AGENT);
}

__global__ __launch_bounds__(256) void gru_init(float* ws, const float* __restrict__ x0) {
  int i = blockIdx.x * blockDim.x + threadIdx.x;
  int stride = gridDim.x * blockDim.x;
  unsigned* w = (unsigned*)ws;
  for (int k = i; k < BUF_BASE; k += stride) w[k] = 0u;
  // xg0[bg][j][b] = x0[(bg*8+b)*512 + j]
  for (int k = i; k < NBG * H_ * BPG; k += stride) {
    int bg = k >> 12, j = (k >> 3) & (H_ - 1), b = k & 7;
    ws[BUF_BASE + k] = x0[(bg * 8 + b) * H_ + j];
  }
}

// Split barrier among the 32 blocks of one batch group.
// arrive: release-add (vmcnt drained by the preceding __syncthreads).
// wait: relaxed poll; data reads are agent-scope so no acquire-inv needed.
__device__ __forceinline__ void gbar_arrive(unsigned* cnt, int idx) {
  __syncthreads();   // drains every wave's outstanding stores (vmcnt(0))
  if (threadIdx.x == 0)
    __hip_atomic_fetch_add(cnt + idx, 1u, __ATOMIC_RELEASE, __HIP_MEMORY_SCOPE_AGENT);
}

__device__ __forceinline__ bool gbar_wait(unsigned* cnt, int idx) {
  __shared__ int s_ok;
  if (threadIdx.x == 0) {
    unsigned* c = cnt + idx;
    int ok = 1;
    int polls = 0;
    while (__hip_atomic_load(c, __ATOMIC_RELAXED, __HIP_MEMORY_SCOPE_AGENT) < (unsigned)NCG) {
      __builtin_amdgcn_s_sleep(1);
      if ((++polls & 255) == 0) {
        if (__hip_atomic_load(cnt + ABORT_IDX, __ATOMIC_RELAXED, __HIP_MEMORY_SCOPE_AGENT) != 0u ||
            polls > 4000000) {
          __hip_atomic_store(cnt + ABORT_IDX, 1u, __ATOMIC_RELAXED, __HIP_MEMORY_SCOPE_AGENT);
          ok = 0;
          break;
        }
      }
    }
    s_ok = ok;
  }
  __syncthreads();
  // compiler-level reordering guard only (no instructions emitted)
  __atomic_signal_fence(__ATOMIC_ACQUIRE);
  return s_ok != 0;
}

__global__ __launch_bounds__(NTHR, 1) void gru_main(
    const float* __restrict__ u, const float* __restrict__ kfz,
    const float* __restrict__ bfz, const float* __restrict__ kr,
    const float* __restrict__ br, const float* __restrict__ wout,
    const float* __restrict__ bout, float* __restrict__ out, float* ws) {
  unsigned* cnt = (unsigned*)ws;
  float* xg0 = ws + BUF_BASE;
  float* xg1 = xg0 + XSLAB;
  float* xfg = xg1 + XSLAB;

  const int bg  = blockIdx.x & 7;
  const int cg  = blockIdx.x >> 3;   // column group 0..31
  const int tid = threadIdx.x;
  const int w   = tid >> 6;          // wave 0..3
  const int l   = tid & 63;
  const int cq  = l & 7;             // col-quad 0..7
  const int g   = l >> 3;            // in-wave k-slice 0..7
  const int kb  = (w * 8 + g) * KSL; // this thread's k base (18 k's)
  const int fc  = tid >> 3;          // finalize col 0..31
  const int fb  = tid & 7;           // finalize batch 0..7
  const int yb  = tid >> 5;          // y batch 0..7
  const int yq  = tid & 31;          // y k-slice 0..31

  __shared__ float bufA[KTOT * RS];  // [k][12]: u_t(k<64) | x or f*x
  __shared__ float pA[4 * 32 * RS];
  __shared__ float pB[4 * 16 * RS];
  __shared__ float rbuf[16 * 8];

  // ---- one-time: weights into registers ----
  float wA[KSL][4];
#pragma unroll
  for (int i = 0; i < KSL; ++i)
#pragma unroll
    for (int m = 0; m < 4; ++m) {
      int c = 4 * cq + m;
      int gcol = (c < 16) ? (16 * cg + c) : (512 + 16 * cg + (c - 16));
      wA[i][m] = kfz[(size_t)(kb + i) * H2_ + gcol];
    }
  float wB[KSL][2];
#pragma unroll
  for (int i = 0; i < KSL; ++i)
#pragma unroll
    for (int m = 0; m < 2; ++m)
      wB[i][m] = kr[(size_t)(kb + i) * H_ + (16 * cg + 2 * cq + m)];
  float wy[16];
#pragma unroll
  for (int i = 0; i < 16; ++i) wy[i] = wout[cg * H_ + (yq + 32 * i)];
  const float by = bout[cg];
  const int fzc = (fc < 16) ? (16 * cg + fc) : (512 + 16 * cg + (fc - 16));
  const float biasA = bfz[fzc];
  const float biasB = (tid < 128) ? br[16 * cg + fc] : 0.0f;

  float zreg = 0.0f, xoldz = 0.0f;

  // u_t=0 into LDS (later steps prefetched during barrier 2)
  {
    int k2 = tid & 31, b = tid >> 5;
    float2 uv = *(const float2*)&u[((size_t)(bg * 8 + b) * T_) * IN_ + 2 * k2];
    bufA[(2 * k2) * RS + b] = uv.x;
    bufA[(2 * k2 + 1) * RS + b] = uv.y;
  }

  for (int t = 0; t < T_; ++t) {
    float* xcur = (t & 1) ? xg1 : xg0;
    float* xnxt = (t & 1) ? xg0 : xg1;

    // ---- stage x into bufA (agent-scope loads: always MALL-fresh) ----
#pragma unroll
    for (int q = 0; q < 8; ++q) {
      bufA[(64 + tid) * RS + q]       = gload(&xcur[(size_t)(bg * H_ + tid) * 8 + q]);
      bufA[(64 + tid + 256) * RS + q] = gload(&xcur[(size_t)(bg * H_ + tid + 256) * 8 + q]);
    }
    __syncthreads();

    // ---- phase A core: fz partials for 4 cols x 8 batches over 18 k ----
    float acc[4][8] = {};
#pragma unroll
    for (int i = 0; i < KSL; ++i) {
      const float* xr = &bufA[(kb + i) * RS];
      float4 x0 = *(const float4*)xr;
      float4 x1 = *(const float4*)(xr + 4);
#pragma unroll
      for (int m = 0; m < 4; ++m) {
        float wv = wA[i][m];
        acc[m][0] += wv * x0.x; acc[m][1] += wv * x0.y;
        acc[m][2] += wv * x0.z; acc[m][3] += wv * x0.w;
        acc[m][4] += wv * x1.x; acc[m][5] += wv * x1.y;
        acc[m][6] += wv * x1.z; acc[m][7] += wv * x1.w;
      }
    }

    // ---- reduce A ----
#pragma unroll
    for (int m = 0; m < 4; ++m)
#pragma unroll
      for (int b = 0; b < 8; ++b) {
        acc[m][b] += __shfl_xor(acc[m][b], 8);
        acc[m][b] += __shfl_xor(acc[m][b], 16);
        acc[m][b] += __shfl_xor(acc[m][b], 32);
      }
    if (g == 0) {
#pragma unroll
      for (int m = 0; m < 4; ++m) {
        float* p = &pA[(w * 32 + 4 * cq + m) * RS];
        *(float4*)p = make_float4(acc[m][0], acc[m][1], acc[m][2], acc[m][3]);
        *(float4*)(p + 4) = make_float4(acc[m][4], acc[m][5], acc[m][6], acc[m][7]);
      }
    }
    __syncthreads();

    // ---- finalize A: sigmoid; publish f*x (MALL store); stash z ----
    {
      float s = pA[(0 * 32 + fc) * RS + fb] + pA[(1 * 32 + fc) * RS + fb] +
                pA[(2 * 32 + fc) * RS + fb] + pA[(3 * 32 + fc) * RS + fb] + biasA;
      float sig = 1.0f / (1.0f + __expf(-s));
      if (fc < 16) {
        float xo = bufA[(64 + 16 * cg + fc) * RS + fb];
        gstore(&xfg[(size_t)(bg * H_ + 16 * cg + fc) * 8 + fb], sig * xo);
      } else {
        zreg = sig;
        xoldz = bufA[(64 + 16 * cg + (fc - 16)) * RS + fb];
      }
    }

    gbar_arrive(cnt, (bg * 2 + 0) * 2048 + t);

    // ---- y_t = x_t @ wout[cg]: overlapped with barrier-1 poll latency ----
    {
      float yp = 0.0f;
#pragma unroll
      for (int i = 0; i < 16; ++i)
        yp += wy[i] * bufA[(64 + yq + 32 * i) * RS + yb];
      yp += __shfl_xor(yp, 1);  yp += __shfl_xor(yp, 2);
      yp += __shfl_xor(yp, 4);  yp += __shfl_xor(yp, 8);
      yp += __shfl_xor(yp, 16);
      if (yq == 0)
        out[((size_t)(bg * 8 + yb) * T_ + t) * OUT_ + cg] = yp + by;
    }

    if (!gbar_wait(cnt, (bg * 2 + 0) * 2048 + t)) return;

    // ---- stage f*x into bufA (agent-scope loads) ----
#pragma unroll
    for (int q = 0; q < 8; ++q) {
      bufA[(64 + tid) * RS + q]       = gload(&xfg[(size_t)(bg * H_ + tid) * 8 + q]);
      bufA[(64 + tid + 256) * RS + q] = gload(&xfg[(size_t)(bg * H_ + tid + 256) * 8 + q]);
    }
    __syncthreads();

    // ---- phase B core: r partials for 2 cols x 8 batches ----
    float acc2[2][8] = {};
#pragma unroll
    for (int i = 0; i < KSL; ++i) {
      const float* xr = &bufA[(kb + i) * RS];
      float4 x0 = *(const float4*)xr;
      float4 x1 = *(const float4*)(xr + 4);
#pragma unroll
      for (int m = 0; m < 2; ++m) {
        float wv = wB[i][m];
        acc2[m][0] += wv * x0.x; acc2[m][1] += wv * x0.y;
        acc2[m][2] += wv * x0.z; acc2[m][3] += wv * x0.w;
        acc2[m][4] += wv * x1.x; acc2[m][5] += wv * x1.y;
        acc2[m][6] += wv * x1.z; acc2[m][7] += wv * x1.w;
      }
    }
#pragma unroll
    for (int m = 0; m < 2; ++m)
#pragma unroll
      for (int b = 0; b < 8; ++b) {
        acc2[m][b] += __shfl_xor(acc2[m][b], 8);
        acc2[m][b] += __shfl_xor(acc2[m][b], 16);
        acc2[m][b] += __shfl_xor(acc2[m][b], 32);
      }
    if (g == 0) {
#pragma unroll
      for (int m = 0; m < 2; ++m) {
        float* p = &pB[(w * 16 + 2 * cq + m) * RS];
        *(float4*)p = make_float4(acc2[m][0], acc2[m][1], acc2[m][2], acc2[m][3]);
        *(float4*)(p + 4) = make_float4(acc2[m][4], acc2[m][5], acc2[m][6], acc2[m][7]);
      }
    }
    __syncthreads();

    // ---- finalize B: tanh -> rbuf ----
    if (tid < 128) {
      float s = pB[(0 * 16 + fc) * RS + fb] + pB[(1 * 16 + fc) * RS + fb] +
                pB[(2 * 16 + fc) * RS + fb] + pB[(3 * 16 + fc) * RS + fb] + biasB;
      float e = __expf(2.0f * s);
      rbuf[fc * 8 + fb] = 1.0f - 2.0f / (1.0f + e);
    }
    __syncthreads();

    // ---- update: x_next = x + z*(r - x) (MALL store) ----
    if (tid >= 128) {
      float r = rbuf[(fc - 16) * 8 + fb];
      float xn = xoldz + zreg * (r - xoldz);
      gstore(&xnxt[(size_t)(bg * H_ + 16 * cg + (fc - 16)) * 8 + fb], xn);
    }

    gbar_arrive(cnt, (bg * 2 + 1) * 2048 + t);

    // ---- prefetch u_{t+1} into LDS while barrier-2 resolves ----
    if (t + 1 < T_) {
      int k2 = tid & 31, b = tid >> 5;
      float2 uv = *(const float2*)&u[((size_t)(bg * 8 + b) * T_ + (t + 1)) * IN_ + 2 * k2];
      bufA[(2 * k2) * RS + b] = uv.x;
      bufA[(2 * k2 + 1) * RS + b] = uv.y;
    }

    if (!gbar_wait(cnt, (bg * 2 + 1) * 2048 + t)) return;
  }
}

extern "C" void kernel_launch(void* const* d_in, const int* in_sizes, int n_in,
                              void* d_out, int out_size, void* d_ws, size_t ws_size,
                              hipStream_t stream) {
  const float* u    = (const float*)d_in[0];
  const float* x0   = (const float*)d_in[1];
  const float* kfz  = (const float*)d_in[2];
  const float* bfz  = (const float*)d_in[3];
  const float* kr   = (const float*)d_in[4];
  const float* br   = (const float*)d_in[5];
  const float* wout = (const float*)d_in[6];
  const float* bout = (const float*)d_in[7];
  float* out = (float*)d_out;
  float* ws  = (float*)d_ws;

  hipLaunchKernelGGL(gru_init, dim3(64), dim3(256), 0, stream, ws, x0);
  hipLaunchKernelGGL(gru_main, dim3(NBG * NCG), dim3(NTHR), 0, stream,
                     u, kfz, bfz, kr, br, wout, bout, out, ws);
}